// Round 1
// baseline (505.171 us; speedup 1.0000x reference)
//
#include <hip/hip_runtime.h>
#include <hip/hip_bf16.h>
#include <math.h>

// Problem constants
// x: [B=16, C=256, H=128, W=128] fp32; plane = 16384 elems; B*C = 4096 planes
#define PLANE 16384
#define PLANE4 4096   // float4 count per plane
#define NPLANES 4096  // B*C
#define NB 16
#define NC 256
#define NR 16

// Kernel 1: per-(b,c) plane mean. One block per plane.
__global__ __launch_bounds__(256) void pool_kernel(const float* __restrict__ x,
                                                   float* __restrict__ mean) {
    const size_t base = (size_t)blockIdx.x * PLANE;
    const float4* xp = (const float4*)(x + base);
    float s = 0.f;
    #pragma unroll 4
    for (int i = threadIdx.x; i < PLANE4; i += 256) {
        float4 v = xp[i];
        s += (v.x + v.y) + (v.z + v.w);
    }
    // wave64 shuffle reduce
    #pragma unroll
    for (int o = 32; o > 0; o >>= 1) s += __shfl_down(s, o, 64);
    __shared__ float ws[4];
    if ((threadIdx.x & 63) == 0) ws[threadIdx.x >> 6] = s;
    __syncthreads();
    if (threadIdx.x == 0) {
        float t = (ws[0] + ws[1]) + (ws[2] + ws[3]);
        mean[blockIdx.x] = t * (1.0f / (float)PLANE);
    }
}

// Kernel 2: tiny MLP. Single block, 256 threads.
// h[b,r] = relu(sum_c y[b,c]*w1[r,c] + b1[r])   (w1: [16,256])
// g[b,c] = sigmoid(sum_r h[b,r]*w2[c,r] + b2[c]) (w2: [256,16])
__global__ __launch_bounds__(256) void mlp_kernel(const float* __restrict__ mean,
                                                  const float* __restrict__ w1,
                                                  const float* __restrict__ b1,
                                                  const float* __restrict__ w2,
                                                  const float* __restrict__ b2,
                                                  float* __restrict__ gate) {
    __shared__ float ysh[NB * NC];   // 16 KiB
    __shared__ float hsh[NB * NR];   // 1 KiB
    for (int i = threadIdx.x; i < NB * NC; i += 256) ysh[i] = mean[i];
    __syncthreads();
    // 256 threads = 16 b * 16 r, each computes one h
    {
        const int b = threadIdx.x >> 4;
        const int r = threadIdx.x & 15;
        float acc = b1[r];
        #pragma unroll 8
        for (int c = 0; c < NC; ++c) acc += ysh[b * NC + c] * w1[r * NC + c];
        hsh[b * NR + r] = fmaxf(acc, 0.f);
    }
    __syncthreads();
    // each thread owns channel c, loops over b
    {
        const int c = threadIdx.x;
        const float bias = b2[c];
        float w2l[NR];
        #pragma unroll
        for (int r = 0; r < NR; ++r) w2l[r] = w2[c * NR + r];
        for (int b = 0; b < NB; ++b) {
            float a = bias;
            #pragma unroll
            for (int r = 0; r < NR; ++r) a += hsh[b * NR + r] * w2l[r];
            gate[b * NC + c] = 1.0f / (1.0f + expf(-a));
        }
    }
}

// Kernel 3: out = x * gate[b,c]. One block per plane, float4 RMW.
__global__ __launch_bounds__(256) void scale_kernel(const float* __restrict__ x,
                                                    const float* __restrict__ gate,
                                                    float* __restrict__ out) {
    const size_t base = (size_t)blockIdx.x * PLANE;
    const float g = gate[blockIdx.x];  // wave-uniform
    const float4* xp = (const float4*)(x + base);
    float4* op = (float4*)(out + base);
    #pragma unroll 4
    for (int i = threadIdx.x; i < PLANE4; i += 256) {
        float4 v = xp[i];
        v.x *= g; v.y *= g; v.z *= g; v.w *= g;
        op[i] = v;
    }
}

extern "C" void kernel_launch(void* const* d_in, const int* in_sizes, int n_in,
                              void* d_out, int out_size, void* d_ws, size_t ws_size,
                              hipStream_t stream) {
    const float* x  = (const float*)d_in[0];
    const float* w1 = (const float*)d_in[1];
    const float* b1 = (const float*)d_in[2];
    const float* w2 = (const float*)d_in[3];
    const float* b2 = (const float*)d_in[4];
    float* out = (float*)d_out;

    float* mean = (float*)d_ws;            // 4096 floats
    float* gate = mean + NPLANES;          // 4096 floats

    pool_kernel<<<NPLANES, 256, 0, stream>>>(x, mean);
    mlp_kernel<<<1, 256, 0, stream>>>(mean, w1, b1, w2, b2, gate);
    scale_kernel<<<NPLANES, 256, 0, stream>>>(x, gate, out);
}

// Round 3
// 481.617 us; speedup vs baseline: 1.0489x; 1.0489x over previous
//
#include <hip/hip_runtime.h>
#include <hip/hip_bf16.h>
#include <math.h>

// x: [B=16, C=256, H=128, W=128] fp32; plane = 16384 elems; B*C = 4096 planes
#define PLANE 16384
#define PLANE4 4096   // float4 count per plane
#define NPLANES 4096  // B*C
#define NB 16
#define NC 256
#define NR 16

typedef float vfloat4 __attribute__((ext_vector_type(4)));  // native vec for builtins

// Kernel 1: per-(b,c) plane mean. One block per plane. Regular (caching) loads
// on purpose: they populate L3 so the scale pass can re-read x from L3.
__global__ __launch_bounds__(256) void pool_kernel(const float* __restrict__ x,
                                                   float* __restrict__ mean) {
    const size_t base = (size_t)blockIdx.x * PLANE;
    const vfloat4* xp = (const vfloat4*)(x + base);
    const int tid = threadIdx.x;
    float s = 0.f;
    #pragma unroll
    for (int j = 0; j < 16; ++j) {           // 16 float4 loads in flight
        vfloat4 v = xp[tid + j * 256];
        s += (v.x + v.y) + (v.z + v.w);
    }
    // wave64 shuffle reduce
    #pragma unroll
    for (int o = 32; o > 0; o >>= 1) s += __shfl_down(s, o, 64);
    __shared__ float wsum[4];
    if ((tid & 63) == 0) wsum[tid >> 6] = s;
    __syncthreads();
    if (tid == 0) {
        float t = (wsum[0] + wsum[1]) + (wsum[2] + wsum[3]);
        mean[blockIdx.x] = t * (1.0f / (float)PLANE);
    }
}

// Kernel 2 (fused gate + scale): one block per plane. Each block redundantly
// computes its own gate scalar from `mean` (w1/w2/mean stay L2-hot), then
// streams the plane with nontemporal stores so `out` doesn't evict x from L3.
// Planes are processed in REVERSE order vs pool so the most-recently-cached
// planes are read first (LIFO reuse; x is exactly L3-sized).
__global__ __launch_bounds__(256) void scale_kernel(const float* __restrict__ x,
                                                    const float* __restrict__ mean,
                                                    const float* __restrict__ w1,
                                                    const float* __restrict__ b1,
                                                    const float* __restrict__ w2,
                                                    const float* __restrict__ b2,
                                                    float* __restrict__ out) {
    const int plane = NPLANES - 1 - blockIdx.x;  // reversed for L3 LIFO reuse
    const int b = plane >> 8;                    // plane / NC
    const int c = plane & (NC - 1);              // plane % NC
    const int tid = threadIdx.x;
    const int wave = tid >> 6;
    const int lane = tid & 63;

    __shared__ float hsh[NR];
    __shared__ float gsh;

    // h[r] = relu(b1[r] + sum_c' mean[b,c'] * w1[r,c']); wave w handles r=4w..4w+3
    {
        const vfloat4 yv = ((const vfloat4*)(mean + b * NC))[lane];  // c' = 4*lane..+3
        #pragma unroll
        for (int k = 0; k < 4; ++k) {
            const int r = wave * 4 + k;
            const vfloat4 wv = ((const vfloat4*)(w1 + r * NC))[lane];
            float p = yv.x * wv.x + yv.y * wv.y + yv.z * wv.z + yv.w * wv.w;
            #pragma unroll
            for (int o = 32; o > 0; o >>= 1) p += __shfl_down(p, o, 64);
            if (lane == 0) hsh[r] = fmaxf(p + b1[r], 0.f);
        }
    }
    __syncthreads();
    if (tid == 0) {
        float a = b2[c];
        #pragma unroll
        for (int r = 0; r < NR; ++r) a += hsh[r] * w2[c * NR + r];
        gsh = 1.0f / (1.0f + expf(-a));
    }
    __syncthreads();
    const float g = gsh;  // wave-uniform gate scalar

    const size_t base = (size_t)plane * PLANE;
    const vfloat4* xp = (const vfloat4*)(x + base);
    vfloat4* op = (vfloat4*)(out + base);
    #pragma unroll
    for (int j = 0; j < 16; ++j) {
        vfloat4 v = xp[tid + j * 256];
        v.x *= g; v.y *= g; v.z *= g; v.w *= g;
        __builtin_nontemporal_store(v, op + tid + j * 256);
    }
}

extern "C" void kernel_launch(void* const* d_in, const int* in_sizes, int n_in,
                              void* d_out, int out_size, void* d_ws, size_t ws_size,
                              hipStream_t stream) {
    const float* x  = (const float*)d_in[0];
    const float* w1 = (const float*)d_in[1];
    const float* b1 = (const float*)d_in[2];
    const float* w2 = (const float*)d_in[3];
    const float* b2 = (const float*)d_in[4];
    float* out = (float*)d_out;

    float* mean = (float*)d_ws;  // 4096 floats

    pool_kernel<<<NPLANES, 256, 0, stream>>>(x, mean);
    scale_kernel<<<NPLANES, 256, 0, stream>>>(x, mean, w1, b1, w2, b2, out);
}